// Round 1
// baseline (1300.443 us; speedup 1.0000x reference)
//
#include <hip/hip_runtime.h>
#include <math.h>

#define F_IN 128
#define TDIM 64
#define NGRAPH 256

__device__ __forceinline__ float gelu_f(float x) {
    float x3 = x * x * x;
    return 0.5f * x * (1.0f + tanhf(0.7978845608028654f * (x + 0.044715f * x3)));
}

// ---------------- degree / CSR build ----------------

__global__ __launch_bounds__(256) void deg_count_kernel(const int* __restrict__ dst,
                                                        int* __restrict__ cnt, int E) {
    int e = blockIdx.x * blockDim.x + threadIdx.x;
    if (e < E) atomicAdd(&cnt[dst[e]], 1);
}

__global__ __launch_bounds__(256) void deg_fin_kernel(const int* __restrict__ cnt,
                                                      float* __restrict__ isq,
                                                      float* __restrict__ dinv, int n) {
    int i = blockIdx.x * blockDim.x + threadIdx.x;
    if (i < n) {
        float d = (float)cnt[i] + 1.0f;  // +1 self loop
        isq[i] = rsqrtf(d);
        dinv[i] = 1.0f / d;
    }
}

// 3-phase exclusive scan of cnt[N] -> row_off[N+1], chunk = 2048 per block
__global__ __launch_bounds__(256) void scanA_kernel(const int* __restrict__ cnt,
                                                    int* __restrict__ bsums, int n) {
    __shared__ int sh[256];
    int t = threadIdx.x;
    int base = blockIdx.x * 2048 + t * 8;
    int s = 0;
    for (int j = 0; j < 8; ++j) {
        int i = base + j;
        if (i < n) s += cnt[i];
    }
    sh[t] = s;
    __syncthreads();
    for (int off = 128; off > 0; off >>= 1) {
        if (t < off) sh[t] += sh[t + off];
        __syncthreads();
    }
    if (t == 0) bsums[blockIdx.x] = sh[0];
}

__global__ void scanB_kernel(int* __restrict__ bsums, int nb, int* __restrict__ row_off) {
    if (threadIdx.x == 0 && blockIdx.x == 0) {
        int c = 0;
        for (int i = 0; i < nb; ++i) {
            int v = bsums[i];
            bsums[i] = c;
            c += v;
        }
        row_off[0] = 0;
    }
}

__global__ __launch_bounds__(256) void scanC_kernel(const int* __restrict__ cnt,
                                                    const int* __restrict__ bsums,
                                                    int* __restrict__ row_off, int n) {
    __shared__ int sh[256];
    int t = threadIdx.x;
    int base = blockIdx.x * 2048 + t * 8;
    int v[8];
    int s = 0;
    for (int j = 0; j < 8; ++j) {
        int i = base + j;
        int x = (i < n) ? cnt[i] : 0;
        s += x;
        v[j] = s;  // local inclusive
    }
    sh[t] = s;
    __syncthreads();
    for (int off = 1; off < 256; off <<= 1) {
        int x = (t >= off) ? sh[t - off] : 0;
        __syncthreads();
        sh[t] += x;
        __syncthreads();
    }
    int threadExcl = sh[t] - s;
    int off0 = bsums[blockIdx.x] + threadExcl;
    for (int j = 0; j < 8; ++j) {
        int i = base + j;
        if (i < n) row_off[i + 1] = off0 + v[j];
    }
}

__global__ __launch_bounds__(256) void fill_edges_kernel(const int* __restrict__ src,
                                                         const int* __restrict__ dst,
                                                         const int* __restrict__ row_off,
                                                         int* __restrict__ cursor,
                                                         const float* __restrict__ isq,
                                                         int* __restrict__ src_s,
                                                         float* __restrict__ nrm_s, int E) {
    int e = blockIdx.x * blockDim.x + threadIdx.x;
    if (e >= E) return;
    int s = src[e];
    int d = dst[e];
    int p = atomicAdd(&cursor[d], 1);
    int idx = row_off[d] + p;
    src_s[idx] = s;
    nrm_s[idx] = isq[s] * isq[d];
}

// ---------------- fp32 GEMM: Y[N,FOUT] = X[N,128] @ W[128,FOUT] ----------------
// block: 256 threads (16x16), tile 128 rows x FOUT cols, thread tile 8 x (FOUT/16)

template <int FOUT>
__global__ __launch_bounds__(256) void gemm_kernel(const float* __restrict__ X,
                                                   const float* __restrict__ W,
                                                   float* __restrict__ Y, int nrows) {
    constexpr int TN = FOUT / 16;
    __shared__ float As[16][128];   // [k][row]
    __shared__ float Ws[16][FOUT];  // [k][col]
    int t = threadIdx.x;
    int tr = t / 16;  // row group 0..15
    int tc = t % 16;  // col group 0..15
    int rowBase = blockIdx.x * 128;
    float acc[8][TN];
#pragma unroll
    for (int i = 0; i < 8; ++i)
#pragma unroll
        for (int j = 0; j < TN; ++j) acc[i][j] = 0.0f;

    for (int k0 = 0; k0 < 128; k0 += 16) {
        // stage A: 128 rows x 16 k
        for (int l = t; l < 512; l += 256) {
            int rr = l >> 2;
            int kk4 = (l & 3) * 4;
            int grow = rowBase + rr;
            float4 v = make_float4(0.f, 0.f, 0.f, 0.f);
            if (grow < nrows) v = *(const float4*)(X + (size_t)grow * 128 + k0 + kk4);
            As[kk4 + 0][rr] = v.x;
            As[kk4 + 1][rr] = v.y;
            As[kk4 + 2][rr] = v.z;
            As[kk4 + 3][rr] = v.w;
        }
        // stage W: 16 x FOUT
        for (int l = t; l < 16 * FOUT / 4; l += 256) {
            int kk = l / (FOUT / 4);
            int cc4 = (l % (FOUT / 4)) * 4;
            *(float4*)&Ws[kk][cc4] = *(const float4*)(W + (size_t)(k0 + kk) * FOUT + cc4);
        }
        __syncthreads();
#pragma unroll
        for (int kk = 0; kk < 16; ++kk) {
            float a[8], b[TN];
#pragma unroll
            for (int i = 0; i < 8; ++i) a[i] = As[kk][tr * 8 + i];
#pragma unroll
            for (int j = 0; j < TN; ++j) b[j] = Ws[kk][tc * TN + j];
#pragma unroll
            for (int i = 0; i < 8; ++i)
#pragma unroll
                for (int j = 0; j < TN; ++j) acc[i][j] += a[i] * b[j];
        }
        __syncthreads();
    }
    for (int i = 0; i < 8; ++i) {
        int grow = rowBase + tr * 8 + i;
        if (grow < nrows) {
#pragma unroll
            for (int j = 0; j < TN; j += 4)
                *(float4*)(Y + (size_t)grow * FOUT + tc * TN + j) = *(float4*)&acc[i][j];
        }
    }
}

// ---------------- edge aggregation + self loop + bias + gelu ----------------
// one wave (64 lanes) per node

template <int F>
__global__ __launch_bounds__(256) void agg_kernel(const float* __restrict__ xl,
                                                  const int* __restrict__ row_off,
                                                  const int* __restrict__ src_s,
                                                  const float* __restrict__ nrm_s,
                                                  const float* __restrict__ dinv,
                                                  const float* __restrict__ bias,
                                                  float* __restrict__ out, int nnodes) {
    int wave = (blockIdx.x * blockDim.x + threadIdx.x) >> 6;
    int lane = threadIdx.x & 63;
    if (wave >= nnodes) return;
    int i = wave;
    int e0 = row_off[i], e1 = row_off[i + 1];
    float acc0 = 0.f, acc1 = 0.f;
    for (int e = e0; e < e1; ++e) {
        int s = src_s[e];
        float nrm = nrm_s[e];
        const float* p = xl + (size_t)s * F;
        acc0 += nrm * p[lane];
        if (F == 128) acc1 += nrm * p[lane + 64];
    }
    float di = dinv[i];
    const float* pi = xl + (size_t)i * F;
    acc0 += di * pi[lane] + bias[lane];
    out[(size_t)i * F + lane] = gelu_f(acc0);
    if (F == 128) {
        acc1 += di * pi[lane + 64] + bias[lane + 64];
        out[(size_t)i * F + 64 + lane] = gelu_f(acc1);
    }
}

// ---------------- mean pool ----------------

__global__ __launch_bounds__(256) void pool_kernel(const float* __restrict__ h,
                                                   const int* __restrict__ batch,
                                                   float* __restrict__ psum,
                                                   float* __restrict__ pcnt, int nnodes) {
    int wave = (blockIdx.x * blockDim.x + threadIdx.x) >> 6;
    int lane = threadIdx.x & 63;
    if (wave >= nnodes) return;
    int g = batch[wave];
    atomicAdd(&psum[g * TDIM + lane], h[(size_t)wave * TDIM + lane]);
    if (lane == 0) atomicAdd(&pcnt[g], 1.0f);
}

__global__ __launch_bounds__(256) void fin_kernel(const float* __restrict__ psum,
                                                  const float* __restrict__ pcnt,
                                                  float* __restrict__ out) {
    int i = blockIdx.x * blockDim.x + threadIdx.x;
    if (i < NGRAPH * TDIM) {
        float c = pcnt[i >> 6];
        out[i] = psum[i] / fmaxf(c, 1.0f);
    }
}

// ---------------- launch ----------------

extern "C" void kernel_launch(void* const* d_in, const int* in_sizes, int n_in,
                              void* d_out, int out_size, void* d_ws, size_t ws_size,
                              hipStream_t stream) {
    const float* x = (const float*)d_in[0];
    const int* ei = (const int*)d_in[1];
    const int* batch = (const int*)d_in[2];
    const float* W0 = (const float*)d_in[3];
    const float* b0 = (const float*)d_in[4];
    const float* W1 = (const float*)d_in[5];
    const float* b1 = (const float*)d_in[6];
    const float* W2 = (const float*)d_in[7];
    const float* b2 = (const float*)d_in[8];

    const int N = in_sizes[0] / F_IN;
    const int E = in_sizes[1] / 2;
    const int* src = ei;
    const int* dst = ei + E;

    char* w = (char*)d_ws;
    auto alloc = [&](size_t bytes) -> void* {
        void* p = (void*)w;
        w += (bytes + 255) & ~(size_t)255;
        return p;
    };
    float* isq = (float*)alloc((size_t)N * 4);
    float* dinv = (float*)alloc((size_t)N * 4);
    int* cnt = (int*)alloc((size_t)N * 4);
    int* cursor = (int*)alloc((size_t)N * 4);
    int* row_off = (int*)alloc((size_t)(N + 1) * 4);
    int* bsums = (int*)alloc(256 * 4);
    int* src_s = (int*)alloc((size_t)E * 4);
    float* nrm_s = (float*)alloc((size_t)E * 4);
    float* psum = (float*)alloc((size_t)NGRAPH * TDIM * 4);
    float* pcnt = (float*)alloc((size_t)NGRAPH * 4);
    float* bufA = (float*)alloc((size_t)N * 128 * 4);
    float* bufB = (float*)alloc((size_t)N * 128 * 4);

    hipMemsetAsync(cnt, 0, (size_t)N * 4, stream);
    hipMemsetAsync(cursor, 0, (size_t)N * 4, stream);
    hipMemsetAsync(psum, 0, (size_t)NGRAPH * TDIM * 4, stream);
    hipMemsetAsync(pcnt, 0, (size_t)NGRAPH * 4, stream);

    const int tb = 256;
    deg_count_kernel<<<(E + tb - 1) / tb, tb, 0, stream>>>(dst, cnt, E);
    deg_fin_kernel<<<(N + tb - 1) / tb, tb, 0, stream>>>(cnt, isq, dinv, N);

    int nchunk = (N + 2047) / 2048;
    scanA_kernel<<<nchunk, 256, 0, stream>>>(cnt, bsums, N);
    scanB_kernel<<<1, 64, 0, stream>>>(bsums, nchunk, row_off);
    scanC_kernel<<<nchunk, 256, 0, stream>>>(cnt, bsums, row_off, N);
    fill_edges_kernel<<<(E + tb - 1) / tb, tb, 0, stream>>>(src, dst, row_off, cursor, isq,
                                                            src_s, nrm_s, E);

    int gblocks = (N + 127) / 128;
    int ablocks = (N * 64 + 255) / 256;

    // layer 0: x @ W0 -> bufA; agg -> bufB
    gemm_kernel<128><<<gblocks, 256, 0, stream>>>(x, W0, bufA, N);
    agg_kernel<128><<<ablocks, 256, 0, stream>>>(bufA, row_off, src_s, nrm_s, dinv, b0, bufB, N);
    // layer 1
    gemm_kernel<128><<<gblocks, 256, 0, stream>>>(bufB, W1, bufA, N);
    agg_kernel<128><<<ablocks, 256, 0, stream>>>(bufA, row_off, src_s, nrm_s, dinv, b1, bufB, N);
    // layer 2 (Fout = 64)
    gemm_kernel<64><<<gblocks, 256, 0, stream>>>(bufB, W2, bufA, N);
    agg_kernel<64><<<ablocks, 256, 0, stream>>>(bufA, row_off, src_s, nrm_s, dinv, b2, bufB, N);

    // pool
    pool_kernel<<<ablocks, 256, 0, stream>>>(bufB, batch, psum, pcnt, N);
    fin_kernel<<<(NGRAPH * TDIM + 255) / 256, 256, 0, stream>>>(psum, pcnt, (float*)d_out);
}

// Round 2
// 952.844 us; speedup vs baseline: 1.3648x; 1.3648x over previous
//
#include <hip/hip_runtime.h>
#include <math.h>

#define F_IN 128
#define TDIM 64
#define NGRAPH 256

__device__ __forceinline__ float gelu_f(float x) {
    float x3 = x * x * x;
    return 0.5f * x * (1.0f + tanhf(0.7978845608028654f * (x + 0.044715f * x3)));
}

// ---------------- degree / CSR build ----------------

__global__ __launch_bounds__(256) void deg_count_kernel(const int* __restrict__ dst,
                                                        int* __restrict__ cnt, int E) {
    int e = blockIdx.x * blockDim.x + threadIdx.x;
    if (e < E) atomicAdd(&cnt[dst[e]], 1);
}

__global__ __launch_bounds__(256) void deg_fin_kernel(const int* __restrict__ cnt,
                                                      float* __restrict__ isq,
                                                      float* __restrict__ dinv, int n) {
    int i = blockIdx.x * blockDim.x + threadIdx.x;
    if (i < n) {
        float d = (float)cnt[i] + 1.0f;  // +1 self loop
        isq[i] = rsqrtf(d);
        dinv[i] = 1.0f / d;
    }
}

// 3-phase exclusive scan of cnt[N] -> row_off[N+1], chunk = 2048 per block
__global__ __launch_bounds__(256) void scanA_kernel(const int* __restrict__ cnt,
                                                    int* __restrict__ bsums, int n) {
    __shared__ int sh[256];
    int t = threadIdx.x;
    int base = blockIdx.x * 2048 + t * 8;
    int s = 0;
    for (int j = 0; j < 8; ++j) {
        int i = base + j;
        if (i < n) s += cnt[i];
    }
    sh[t] = s;
    __syncthreads();
    for (int off = 128; off > 0; off >>= 1) {
        if (t < off) sh[t] += sh[t + off];
        __syncthreads();
    }
    if (t == 0) bsums[blockIdx.x] = sh[0];
}

__global__ void scanB_kernel(int* __restrict__ bsums, int nb, int* __restrict__ row_off) {
    if (threadIdx.x == 0 && blockIdx.x == 0) {
        int c = 0;
        for (int i = 0; i < nb; ++i) {
            int v = bsums[i];
            bsums[i] = c;
            c += v;
        }
        row_off[0] = 0;
    }
}

__global__ __launch_bounds__(256) void scanC_kernel(const int* __restrict__ cnt,
                                                    const int* __restrict__ bsums,
                                                    int* __restrict__ row_off, int n) {
    __shared__ int sh[256];
    int t = threadIdx.x;
    int base = blockIdx.x * 2048 + t * 8;
    int v[8];
    int s = 0;
    for (int j = 0; j < 8; ++j) {
        int i = base + j;
        int x = (i < n) ? cnt[i] : 0;
        s += x;
        v[j] = s;  // local inclusive
    }
    sh[t] = s;
    __syncthreads();
    for (int off = 1; off < 256; off <<= 1) {
        int x = (t >= off) ? sh[t - off] : 0;
        __syncthreads();
        sh[t] += x;
        __syncthreads();
    }
    int threadExcl = sh[t] - s;
    int off0 = bsums[blockIdx.x] + threadExcl;
    for (int j = 0; j < 8; ++j) {
        int i = base + j;
        if (i < n) row_off[i + 1] = off0 + v[j];
    }
}

__global__ __launch_bounds__(256) void fill_edges_kernel(const int* __restrict__ src,
                                                         const int* __restrict__ dst,
                                                         const int* __restrict__ row_off,
                                                         int* __restrict__ cursor,
                                                         const float* __restrict__ isq,
                                                         int* __restrict__ src_s,
                                                         float* __restrict__ nrm_s, int E) {
    int e = blockIdx.x * blockDim.x + threadIdx.x;
    if (e >= E) return;
    int s = src[e];
    int d = dst[e];
    int p = atomicAdd(&cursor[d], 1);
    int idx = row_off[d] + p;
    src_s[idx] = s;
    nrm_s[idx] = isq[s] * isq[d];
}

// ---------------- fp32 GEMM: Y[N,FOUT] = X[N,128] @ W[128,FOUT] ----------------
// block: 256 threads (16x16), tile 128 rows x FOUT cols, thread tile 8 x (FOUT/16)

template <int FOUT>
__global__ __launch_bounds__(256) void gemm_kernel(const float* __restrict__ X,
                                                   const float* __restrict__ W,
                                                   float* __restrict__ Y, int nrows) {
    constexpr int TN = FOUT / 16;
    __shared__ float As[16][128];   // [k][row]
    __shared__ float Ws[16][FOUT];  // [k][col]
    int t = threadIdx.x;
    int tr = t / 16;  // row group 0..15
    int tc = t % 16;  // col group 0..15
    int rowBase = blockIdx.x * 128;
    float acc[8][TN];
#pragma unroll
    for (int i = 0; i < 8; ++i)
#pragma unroll
        for (int j = 0; j < TN; ++j) acc[i][j] = 0.0f;

    for (int k0 = 0; k0 < 128; k0 += 16) {
        // stage A: 128 rows x 16 k
        for (int l = t; l < 512; l += 256) {
            int rr = l >> 2;
            int kk4 = (l & 3) * 4;
            int grow = rowBase + rr;
            float4 v = make_float4(0.f, 0.f, 0.f, 0.f);
            if (grow < nrows) v = *(const float4*)(X + (size_t)grow * 128 + k0 + kk4);
            As[kk4 + 0][rr] = v.x;
            As[kk4 + 1][rr] = v.y;
            As[kk4 + 2][rr] = v.z;
            As[kk4 + 3][rr] = v.w;
        }
        // stage W: 16 x FOUT
        for (int l = t; l < 16 * FOUT / 4; l += 256) {
            int kk = l / (FOUT / 4);
            int cc4 = (l % (FOUT / 4)) * 4;
            *(float4*)&Ws[kk][cc4] = *(const float4*)(W + (size_t)(k0 + kk) * FOUT + cc4);
        }
        __syncthreads();
#pragma unroll
        for (int kk = 0; kk < 16; ++kk) {
            float a[8], b[TN];
#pragma unroll
            for (int i = 0; i < 8; ++i) a[i] = As[kk][tr * 8 + i];
#pragma unroll
            for (int j = 0; j < TN; ++j) b[j] = Ws[kk][tc * TN + j];
#pragma unroll
            for (int i = 0; i < 8; ++i)
#pragma unroll
                for (int j = 0; j < TN; ++j) acc[i][j] += a[i] * b[j];
        }
        __syncthreads();
    }
    for (int i = 0; i < 8; ++i) {
        int grow = rowBase + tr * 8 + i;
        if (grow < nrows) {
#pragma unroll
            for (int j = 0; j < TN; j += 4)
                *(float4*)(Y + (size_t)grow * FOUT + tc * TN + j) = *(float4*)&acc[i][j];
        }
    }
}

// ---------------- edge aggregation + self loop + bias + gelu ----------------
// one wave (64 lanes) per node

template <int F>
__global__ __launch_bounds__(256) void agg_kernel(const float* __restrict__ xl,
                                                  const int* __restrict__ row_off,
                                                  const int* __restrict__ src_s,
                                                  const float* __restrict__ nrm_s,
                                                  const float* __restrict__ dinv,
                                                  const float* __restrict__ bias,
                                                  float* __restrict__ out, int nnodes) {
    int wave = (blockIdx.x * blockDim.x + threadIdx.x) >> 6;
    int lane = threadIdx.x & 63;
    if (wave >= nnodes) return;
    int i = wave;
    int e0 = row_off[i], e1 = row_off[i + 1];
    float acc0 = 0.f, acc1 = 0.f;
    for (int e = e0; e < e1; ++e) {
        int s = src_s[e];
        float nrm = nrm_s[e];
        const float* p = xl + (size_t)s * F;
        acc0 += nrm * p[lane];
        if (F == 128) acc1 += nrm * p[lane + 64];
    }
    float di = dinv[i];
    const float* pi = xl + (size_t)i * F;
    acc0 += di * pi[lane] + bias[lane];
    out[(size_t)i * F + lane] = gelu_f(acc0);
    if (F == 128) {
        acc1 += di * pi[lane + 64] + bias[lane + 64];
        out[(size_t)i * F + 64 + lane] = gelu_f(acc1);
    }
}

// ---------------- mean pool (batch is sorted: segment-accumulate per wave chunk) ----------------
// One wave handles CHUNK consecutive nodes; registers accumulate a running
// segment sum, flushed with one atomicAdd per (chunk x segment boundary).

#define POOL_CHUNK 64

__global__ __launch_bounds__(256) void pool_kernel(const float* __restrict__ h,
                                                   const int* __restrict__ batch,
                                                   float* __restrict__ psum,
                                                   float* __restrict__ pcnt, int nnodes) {
    int wave = (blockIdx.x * blockDim.x + threadIdx.x) >> 6;
    int lane = threadIdx.x & 63;
    int n0 = wave * POOL_CHUNK;
    if (n0 >= nnodes) return;
    int n1 = n0 + POOL_CHUNK;
    if (n1 > nnodes) n1 = nnodes;

    int g_cur = batch[n0];
    float acc = 0.f;
    int cnt = 0;
    for (int node = n0; node < n1; ++node) {
        int g = batch[node];
        if (g != g_cur) {
            atomicAdd(&psum[g_cur * TDIM + lane], acc);
            if (lane == 0) atomicAdd(&pcnt[g_cur], (float)cnt);
            acc = 0.f;
            cnt = 0;
            g_cur = g;
        }
        acc += h[(size_t)node * TDIM + lane];
        ++cnt;
    }
    atomicAdd(&psum[g_cur * TDIM + lane], acc);
    if (lane == 0) atomicAdd(&pcnt[g_cur], (float)cnt);
}

__global__ __launch_bounds__(256) void fin_kernel(const float* __restrict__ psum,
                                                  const float* __restrict__ pcnt,
                                                  float* __restrict__ out) {
    int i = blockIdx.x * blockDim.x + threadIdx.x;
    if (i < NGRAPH * TDIM) {
        float c = pcnt[i >> 6];
        out[i] = psum[i] / fmaxf(c, 1.0f);
    }
}

// ---------------- launch ----------------

extern "C" void kernel_launch(void* const* d_in, const int* in_sizes, int n_in,
                              void* d_out, int out_size, void* d_ws, size_t ws_size,
                              hipStream_t stream) {
    const float* x = (const float*)d_in[0];
    const int* ei = (const int*)d_in[1];
    const int* batch = (const int*)d_in[2];
    const float* W0 = (const float*)d_in[3];
    const float* b0 = (const float*)d_in[4];
    const float* W1 = (const float*)d_in[5];
    const float* b1 = (const float*)d_in[6];
    const float* W2 = (const float*)d_in[7];
    const float* b2 = (const float*)d_in[8];

    const int N = in_sizes[0] / F_IN;
    const int E = in_sizes[1] / 2;
    const int* src = ei;
    const int* dst = ei + E;

    char* w = (char*)d_ws;
    auto alloc = [&](size_t bytes) -> void* {
        void* p = (void*)w;
        w += (bytes + 255) & ~(size_t)255;
        return p;
    };
    float* isq = (float*)alloc((size_t)N * 4);
    float* dinv = (float*)alloc((size_t)N * 4);
    int* cnt = (int*)alloc((size_t)N * 4);
    int* cursor = (int*)alloc((size_t)N * 4);
    int* row_off = (int*)alloc((size_t)(N + 1) * 4);
    int* bsums = (int*)alloc(256 * 4);
    int* src_s = (int*)alloc((size_t)E * 4);
    float* nrm_s = (float*)alloc((size_t)E * 4);
    float* psum = (float*)alloc((size_t)NGRAPH * TDIM * 4);
    float* pcnt = (float*)alloc((size_t)NGRAPH * 4);
    float* bufA = (float*)alloc((size_t)N * 128 * 4);
    float* bufB = (float*)alloc((size_t)N * 128 * 4);

    hipMemsetAsync(cnt, 0, (size_t)N * 4, stream);
    hipMemsetAsync(cursor, 0, (size_t)N * 4, stream);
    hipMemsetAsync(psum, 0, (size_t)NGRAPH * TDIM * 4, stream);
    hipMemsetAsync(pcnt, 0, (size_t)NGRAPH * 4, stream);

    const int tb = 256;
    deg_count_kernel<<<(E + tb - 1) / tb, tb, 0, stream>>>(dst, cnt, E);
    deg_fin_kernel<<<(N + tb - 1) / tb, tb, 0, stream>>>(cnt, isq, dinv, N);

    int nchunk = (N + 2047) / 2048;
    scanA_kernel<<<nchunk, 256, 0, stream>>>(cnt, bsums, N);
    scanB_kernel<<<1, 64, 0, stream>>>(bsums, nchunk, row_off);
    scanC_kernel<<<nchunk, 256, 0, stream>>>(cnt, bsums, row_off, N);
    fill_edges_kernel<<<(E + tb - 1) / tb, tb, 0, stream>>>(src, dst, row_off, cursor, isq,
                                                            src_s, nrm_s, E);

    int gblocks = (N + 127) / 128;
    int ablocks = (N * 64 + 255) / 256;

    // layer 0: x @ W0 -> bufA; agg -> bufB
    gemm_kernel<128><<<gblocks, 256, 0, stream>>>(x, W0, bufA, N);
    agg_kernel<128><<<ablocks, 256, 0, stream>>>(bufA, row_off, src_s, nrm_s, dinv, b0, bufB, N);
    // layer 1
    gemm_kernel<128><<<gblocks, 256, 0, stream>>>(bufB, W1, bufA, N);
    agg_kernel<128><<<ablocks, 256, 0, stream>>>(bufA, row_off, src_s, nrm_s, dinv, b1, bufB, N);
    // layer 2 (Fout = 64)
    gemm_kernel<64><<<gblocks, 256, 0, stream>>>(bufB, W2, bufA, N);
    agg_kernel<64><<<ablocks, 256, 0, stream>>>(bufA, row_off, src_s, nrm_s, dinv, b2, bufB, N);

    // pool (one wave per POOL_CHUNK nodes)
    int pwaves = (N + POOL_CHUNK - 1) / POOL_CHUNK;
    int pblocks = (pwaves * 64 + 255) / 256;
    pool_kernel<<<pblocks, 256, 0, stream>>>(bufB, batch, psum, pcnt, N);
    fin_kernel<<<(NGRAPH * TDIM + 255) / 256, 256, 0, stream>>>(psum, pcnt, (float*)d_out);
}

// Round 3
// 760.782 us; speedup vs baseline: 1.7094x; 1.2525x over previous
//
#include <hip/hip_runtime.h>
#include <math.h>

#define F_IN 128
#define TDIM 64
#define NGRAPH 256

__device__ __forceinline__ float gelu_f(float x) {
    float x3 = x * x * x;
    return 0.5f * x * (1.0f + tanhf(0.7978845608028654f * (x + 0.044715f * x3)));
}

// ---------------- degree / CSR build ----------------

__global__ __launch_bounds__(256) void deg_count_kernel(const int* __restrict__ dst,
                                                        int* __restrict__ cnt, int E) {
    int e = blockIdx.x * blockDim.x + threadIdx.x;
    if (e < E) atomicAdd(&cnt[dst[e]], 1);
}

__global__ __launch_bounds__(256) void deg_fin_kernel(const int* __restrict__ cnt,
                                                      float* __restrict__ isq,
                                                      float* __restrict__ dinv, int n) {
    int i = blockIdx.x * blockDim.x + threadIdx.x;
    if (i < n) {
        float d = (float)cnt[i] + 1.0f;  // +1 self loop
        isq[i] = rsqrtf(d);
        dinv[i] = 1.0f / d;
    }
}

// 3-phase exclusive scan of cnt[N] -> row_off[N+1], chunk = 2048 per block
__global__ __launch_bounds__(256) void scanA_kernel(const int* __restrict__ cnt,
                                                    int* __restrict__ bsums, int n) {
    __shared__ int sh[256];
    int t = threadIdx.x;
    int base = blockIdx.x * 2048 + t * 8;
    int s = 0;
    for (int j = 0; j < 8; ++j) {
        int i = base + j;
        if (i < n) s += cnt[i];
    }
    sh[t] = s;
    __syncthreads();
    for (int off = 128; off > 0; off >>= 1) {
        if (t < off) sh[t] += sh[t + off];
        __syncthreads();
    }
    if (t == 0) bsums[blockIdx.x] = sh[0];
}

__global__ void scanB_kernel(int* __restrict__ bsums, int nb, int* __restrict__ row_off) {
    if (threadIdx.x == 0 && blockIdx.x == 0) {
        int c = 0;
        for (int i = 0; i < nb; ++i) {
            int v = bsums[i];
            bsums[i] = c;
            c += v;
        }
        row_off[0] = 0;
    }
}

__global__ __launch_bounds__(256) void scanC_kernel(const int* __restrict__ cnt,
                                                    const int* __restrict__ bsums,
                                                    int* __restrict__ row_off, int n) {
    __shared__ int sh[256];
    int t = threadIdx.x;
    int base = blockIdx.x * 2048 + t * 8;
    int v[8];
    int s = 0;
    for (int j = 0; j < 8; ++j) {
        int i = base + j;
        int x = (i < n) ? cnt[i] : 0;
        s += x;
        v[j] = s;  // local inclusive
    }
    sh[t] = s;
    __syncthreads();
    for (int off = 1; off < 256; off <<= 1) {
        int x = (t >= off) ? sh[t - off] : 0;
        __syncthreads();
        sh[t] += x;
        __syncthreads();
    }
    int threadExcl = sh[t] - s;
    int off0 = bsums[blockIdx.x] + threadExcl;
    for (int j = 0; j < 8; ++j) {
        int i = base + j;
        if (i < n) row_off[i + 1] = off0 + v[j];
    }
}

__global__ __launch_bounds__(256) void fill_edges_kernel(const int* __restrict__ src,
                                                         const int* __restrict__ dst,
                                                         const int* __restrict__ row_off,
                                                         int* __restrict__ cursor,
                                                         const float* __restrict__ isq,
                                                         int* __restrict__ src_s,
                                                         float* __restrict__ nrm_s, int E) {
    int e = blockIdx.x * blockDim.x + threadIdx.x;
    if (e >= E) return;
    int s = src[e];
    int d = dst[e];
    int p = atomicAdd(&cursor[d], 1);
    int idx = row_off[d] + p;
    src_s[idx] = s;
    nrm_s[idx] = isq[s] * isq[d];
}

// ---------------- fp32 GEMM: Y[N,FOUT] = X[N,128] @ W[128,FOUT] ----------------
// block: 256 threads (16x16), tile 128 rows x FOUT cols, thread tile 8 x (FOUT/16)

template <int FOUT>
__global__ __launch_bounds__(256) void gemm_kernel(const float* __restrict__ X,
                                                   const float* __restrict__ W,
                                                   float* __restrict__ Y, int nrows) {
    constexpr int TN = FOUT / 16;
    __shared__ float As[16][128];   // [k][row]
    __shared__ float Ws[16][FOUT];  // [k][col]
    int t = threadIdx.x;
    int tr = t / 16;  // row group 0..15
    int tc = t % 16;  // col group 0..15
    int rowBase = blockIdx.x * 128;
    float acc[8][TN];
#pragma unroll
    for (int i = 0; i < 8; ++i)
#pragma unroll
        for (int j = 0; j < TN; ++j) acc[i][j] = 0.0f;

    for (int k0 = 0; k0 < 128; k0 += 16) {
        // stage A: 128 rows x 16 k
        for (int l = t; l < 512; l += 256) {
            int rr = l >> 2;
            int kk4 = (l & 3) * 4;
            int grow = rowBase + rr;
            float4 v = make_float4(0.f, 0.f, 0.f, 0.f);
            if (grow < nrows) v = *(const float4*)(X + (size_t)grow * 128 + k0 + kk4);
            As[kk4 + 0][rr] = v.x;
            As[kk4 + 1][rr] = v.y;
            As[kk4 + 2][rr] = v.z;
            As[kk4 + 3][rr] = v.w;
        }
        // stage W: 16 x FOUT
        for (int l = t; l < 16 * FOUT / 4; l += 256) {
            int kk = l / (FOUT / 4);
            int cc4 = (l % (FOUT / 4)) * 4;
            *(float4*)&Ws[kk][cc4] = *(const float4*)(W + (size_t)(k0 + kk) * FOUT + cc4);
        }
        __syncthreads();
#pragma unroll
        for (int kk = 0; kk < 16; ++kk) {
            float a[8], b[TN];
#pragma unroll
            for (int i = 0; i < 8; ++i) a[i] = As[kk][tr * 8 + i];
#pragma unroll
            for (int j = 0; j < TN; ++j) b[j] = Ws[kk][tc * TN + j];
#pragma unroll
            for (int i = 0; i < 8; ++i)
#pragma unroll
                for (int j = 0; j < TN; ++j) acc[i][j] += a[i] * b[j];
        }
        __syncthreads();
    }
    for (int i = 0; i < 8; ++i) {
        int grow = rowBase + tr * 8 + i;
        if (grow < nrows) {
#pragma unroll
            for (int j = 0; j < TN; j += 4)
                *(float4*)(Y + (size_t)grow * FOUT + tc * TN + j) = *(float4*)&acc[i][j];
        }
    }
}

// ---------------- edge aggregation + self loop + bias + gelu ----------------
// one wave (64 lanes) per node; edge loop manually unrolled x8 so up to 16
// independent 256B-coalesced gathers are in flight per wave (latency hiding)

template <int F>
__global__ __launch_bounds__(256) void agg_kernel(const float* __restrict__ xl,
                                                  const int* __restrict__ row_off,
                                                  const int* __restrict__ src_s,
                                                  const float* __restrict__ nrm_s,
                                                  const float* __restrict__ dinv,
                                                  const float* __restrict__ bias,
                                                  float* __restrict__ out, int nnodes) {
    int wave = (blockIdx.x * blockDim.x + threadIdx.x) >> 6;
    int lane = threadIdx.x & 63;
    if (wave >= nnodes) return;
    int i = wave;
    int e0 = row_off[i], e1 = row_off[i + 1];
    float acc0 = 0.f, acc1 = 0.f;
    int e = e0;
    for (; e + 8 <= e1; e += 8) {
        int s[8];
        float nw[8];
#pragma unroll
        for (int j = 0; j < 8; ++j) s[j] = src_s[e + j];
#pragma unroll
        for (int j = 0; j < 8; ++j) nw[j] = nrm_s[e + j];
        float va[8], vb[8];
#pragma unroll
        for (int j = 0; j < 8; ++j) {
            const float* p = xl + (size_t)s[j] * F;
            va[j] = p[lane];
            if (F == 128) vb[j] = p[lane + 64];
        }
#pragma unroll
        for (int j = 0; j < 8; ++j) {
            acc0 += nw[j] * va[j];
            if (F == 128) acc1 += nw[j] * vb[j];
        }
    }
    for (; e < e1; ++e) {
        int s = src_s[e];
        float nrm = nrm_s[e];
        const float* p = xl + (size_t)s * F;
        acc0 += nrm * p[lane];
        if (F == 128) acc1 += nrm * p[lane + 64];
    }
    float di = dinv[i];
    const float* pi = xl + (size_t)i * F;
    acc0 += di * pi[lane] + bias[lane];
    out[(size_t)i * F + lane] = gelu_f(acc0);
    if (F == 128) {
        acc1 += di * pi[lane + 64] + bias[lane + 64];
        out[(size_t)i * F + 64 + lane] = gelu_f(acc1);
    }
}

// ---------------- mean pool (batch is sorted: segment-accumulate per wave chunk) ----------------

#define POOL_CHUNK 64

__global__ __launch_bounds__(256) void pool_kernel(const float* __restrict__ h,
                                                   const int* __restrict__ batch,
                                                   float* __restrict__ psum,
                                                   float* __restrict__ pcnt, int nnodes) {
    int wave = (blockIdx.x * blockDim.x + threadIdx.x) >> 6;
    int lane = threadIdx.x & 63;
    int n0 = wave * POOL_CHUNK;
    if (n0 >= nnodes) return;
    int n1 = n0 + POOL_CHUNK;
    if (n1 > nnodes) n1 = nnodes;

    int g_cur = batch[n0];
    float acc = 0.f;
    int cnt = 0;
    for (int node = n0; node < n1; ++node) {
        int g = batch[node];
        if (g != g_cur) {
            atomicAdd(&psum[g_cur * TDIM + lane], acc);
            if (lane == 0) atomicAdd(&pcnt[g_cur], (float)cnt);
            acc = 0.f;
            cnt = 0;
            g_cur = g;
        }
        acc += h[(size_t)node * TDIM + lane];
        ++cnt;
    }
    atomicAdd(&psum[g_cur * TDIM + lane], acc);
    if (lane == 0) atomicAdd(&pcnt[g_cur], (float)cnt);
}

__global__ __launch_bounds__(256) void fin_kernel(const float* __restrict__ psum,
                                                  const float* __restrict__ pcnt,
                                                  float* __restrict__ out) {
    int i = blockIdx.x * blockDim.x + threadIdx.x;
    if (i < NGRAPH * TDIM) {
        float c = pcnt[i >> 6];
        out[i] = psum[i] / fmaxf(c, 1.0f);
    }
}

// ---------------- launch ----------------

extern "C" void kernel_launch(void* const* d_in, const int* in_sizes, int n_in,
                              void* d_out, int out_size, void* d_ws, size_t ws_size,
                              hipStream_t stream) {
    const float* x = (const float*)d_in[0];
    const int* ei = (const int*)d_in[1];
    const int* batch = (const int*)d_in[2];
    const float* W0 = (const float*)d_in[3];
    const float* b0 = (const float*)d_in[4];
    const float* W1 = (const float*)d_in[5];
    const float* b1 = (const float*)d_in[6];
    const float* W2 = (const float*)d_in[7];
    const float* b2 = (const float*)d_in[8];

    const int N = in_sizes[0] / F_IN;
    const int E = in_sizes[1] / 2;
    const int* src = ei;
    const int* dst = ei + E;

    char* w = (char*)d_ws;
    auto alloc = [&](size_t bytes) -> void* {
        void* p = (void*)w;
        w += (bytes + 255) & ~(size_t)255;
        return p;
    };
    float* isq = (float*)alloc((size_t)N * 4);
    float* dinv = (float*)alloc((size_t)N * 4);
    int* cnt = (int*)alloc((size_t)N * 4);
    int* cursor = (int*)alloc((size_t)N * 4);
    int* row_off = (int*)alloc((size_t)(N + 1) * 4);
    int* bsums = (int*)alloc(256 * 4);
    int* src_s = (int*)alloc((size_t)E * 4);
    float* nrm_s = (float*)alloc((size_t)E * 4);
    float* psum = (float*)alloc((size_t)NGRAPH * TDIM * 4);
    float* pcnt = (float*)alloc((size_t)NGRAPH * 4);
    float* bufA = (float*)alloc((size_t)N * 128 * 4);
    float* bufB = (float*)alloc((size_t)N * 128 * 4);

    hipMemsetAsync(cnt, 0, (size_t)N * 4, stream);
    hipMemsetAsync(cursor, 0, (size_t)N * 4, stream);
    hipMemsetAsync(psum, 0, (size_t)NGRAPH * TDIM * 4, stream);
    hipMemsetAsync(pcnt, 0, (size_t)NGRAPH * 4, stream);

    const int tb = 256;
    deg_count_kernel<<<(E + tb - 1) / tb, tb, 0, stream>>>(dst, cnt, E);
    deg_fin_kernel<<<(N + tb - 1) / tb, tb, 0, stream>>>(cnt, isq, dinv, N);

    int nchunk = (N + 2047) / 2048;
    scanA_kernel<<<nchunk, 256, 0, stream>>>(cnt, bsums, N);
    scanB_kernel<<<1, 64, 0, stream>>>(bsums, nchunk, row_off);
    scanC_kernel<<<nchunk, 256, 0, stream>>>(cnt, bsums, row_off, N);
    fill_edges_kernel<<<(E + tb - 1) / tb, tb, 0, stream>>>(src, dst, row_off, cursor, isq,
                                                            src_s, nrm_s, E);

    int gblocks = (N + 127) / 128;
    int ablocks = (N * 64 + 255) / 256;

    // layer 0: x @ W0 -> bufA; agg -> bufB
    gemm_kernel<128><<<gblocks, 256, 0, stream>>>(x, W0, bufA, N);
    agg_kernel<128><<<ablocks, 256, 0, stream>>>(bufA, row_off, src_s, nrm_s, dinv, b0, bufB, N);
    // layer 1
    gemm_kernel<128><<<gblocks, 256, 0, stream>>>(bufB, W1, bufA, N);
    agg_kernel<128><<<ablocks, 256, 0, stream>>>(bufA, row_off, src_s, nrm_s, dinv, b1, bufB, N);
    // layer 2 (Fout = 64)
    gemm_kernel<64><<<gblocks, 256, 0, stream>>>(bufB, W2, bufA, N);
    agg_kernel<64><<<ablocks, 256, 0, stream>>>(bufA, row_off, src_s, nrm_s, dinv, b2, bufB, N);

    // pool (one wave per POOL_CHUNK nodes)
    int pwaves = (N + POOL_CHUNK - 1) / POOL_CHUNK;
    int pblocks = (pwaves * 64 + 255) / 256;
    pool_kernel<<<pblocks, 256, 0, stream>>>(bufB, batch, psum, pcnt, N);
    fin_kernel<<<(NGRAPH * TDIM + 255) / 256, 256, 0, stream>>>(psum, pcnt, (float*)d_out);
}